// Round 10
// baseline (171.987 us; speedup 1.0000x reference)
//
#include <hip/hip_runtime.h>

// ---------------------------------------------------------------------------
// Causal MHSA. B=2, T=2048, D=1024, H=16, hd=64. fp32 in -> bf16 internal ->
// fp32 out. R21: GEMMs keep the proven m97 2-barrier/BK=32 loop and tiles,
// but switch to 512-thread blocks (8 waves, half-size per-wave output):
// qkv 12->24 waves/CU (launch_bounds(512,6)), out 8->16 waves/CU — the
// GEMMs are latency-bound at 2-3 blocks/CU grid-limited occupancy.
// attn/canon = R20 exact (paired tiles + gload_lds dbuf + swizzle +
// MFMA-lsum; ~41us).
// ---------------------------------------------------------------------------

#define T_SEQ 2048
#define D_MODEL 1024
#define NEG_BIG (-1.0e30f)
#define Q_SCALE 0.18033688f   // 0.125 * log2(e): attention uses exp2 directly

typedef float f32x4 __attribute__((ext_vector_type(4)));
typedef short s16x8 __attribute__((ext_vector_type(8)));
typedef __bf16 bf16x8 __attribute__((ext_vector_type(8)));

__device__ __forceinline__ f32x4 mfma16(s16x8 a, s16x8 b, f32x4 c) {
    // C[m][n]=sum_k A[m][k]B[n][k]; lane: a=A[m=l16][k=quad*8+j],
    // b=B[n=l16][k=quad*8+j]; C: col(l16)=n, row(quad*4+r)=m
    return __builtin_amdgcn_mfma_f32_16x16x32_bf16(
        __builtin_bit_cast(bf16x8, a), __builtin_bit_cast(bf16x8, b), c, 0, 0, 0);
}

__device__ __forceinline__ short f2bf(float f) {          // RNE
    unsigned int u = __float_as_uint(f);
    u += 0x7fffu + ((u >> 16) & 1u);
    return (short)(u >> 16);
}
__device__ __forceinline__ float bf2f(short s) {
    return __uint_as_float(((unsigned int)(unsigned short)s) << 16);
}
__device__ __forceinline__ unsigned cvt_pk_bf16(float lo, float hi) {
    unsigned r;
    asm("v_cvt_pk_bf16_f32 %0, %1, %2" : "=v"(r) : "v"(lo), "v"(hi));
    return r;
}

__device__ __forceinline__ void async_lds16(const short* g, short* l) {
    __builtin_amdgcn_global_load_lds(
        (const __attribute__((address_space(1))) unsigned int*)g,
        (__attribute__((address_space(3))) unsigned int*)l, 16, 0, 0);
}

// ---------------------------------------------------------------------------
// Fused canon: five fp32 inputs -> bf16, float4-vectorized, one launch.
// ---------------------------------------------------------------------------
#define N_X   4194304
#define N_WI  3145728
#define N_BI  3072
#define N_WO  1048576
#define N_BO  1024
#define V_X   (N_X  / 4)
#define V_WI  (N_WI / 4)
#define V_BI  (N_BI / 4)
#define V_WO  (N_WO / 4)
#define V_BO  (N_BO / 4)
#define V_TOT (V_X + V_WI + V_BI + V_WO + V_BO)

__global__ __launch_bounds__(256) void canon_all_kernel(
    const float* __restrict__ x, const float* __restrict__ wi,
    const float* __restrict__ bi, const float* __restrict__ wo,
    const float* __restrict__ bo,
    short* __restrict__ xb, short* __restrict__ wib, short* __restrict__ bib,
    short* __restrict__ wob, short* __restrict__ bob)
{
    int i = blockIdx.x * 256 + threadIdx.x;
    if (i >= V_TOT) return;
    const float* src; short* dst; int off;
    if      (i < V_X)                    { src = x;  dst = xb;  off = i; }
    else if (i < V_X+V_WI)               { src = wi; dst = wib; off = i - V_X; }
    else if (i < V_X+V_WI+V_BI)          { src = bi; dst = bib; off = i - V_X - V_WI; }
    else if (i < V_X+V_WI+V_BI+V_WO)     { src = wo; dst = wob; off = i - V_X - V_WI - V_BI; }
    else                                 { src = bo; dst = bob; off = i - V_X - V_WI - V_BI - V_WO; }
    float4 v = ((const float4*)src)[off];
    short4 o = { f2bf(v.x), f2bf(v.y), f2bf(v.z), f2bf(v.w) };
    ((short4*)dst)[off] = o;
}

// ---------------------------------------------------------------------------
// GEMM1 (m97 2-barrier loop, BK=32, 512 threads / 8 waves): qkv = x@w_in^T+b.
// Wave w: rows wm=(w&3)*32 (+0/16), cols wn=(w>>2)*64 (+j*16). acc[2][4].
// Staging: wave w gload_lds A rows w*16.. and B rows w*16.. (2 instrs/wave).
// q(xQ_SCALE)/k -> [B,H,T,64]; v -> Vt [B,H,64,T] (transpose fused).
// ---------------------------------------------------------------------------
__global__ __launch_bounds__(512, 6) void gemm_qkv_kernel(
    const short* __restrict__ A, const short* __restrict__ B,
    const short* __restrict__ bias,
    short* __restrict__ qo, short* __restrict__ ko, short* __restrict__ vto)
{
    const int K = 1024;
    alignas(16) __shared__ short As[128][32];
    alignas(16) __shared__ short Bs[128][32];
    const int m0 = blockIdx.x * 128;
    const int n0 = blockIdx.y * 128;
    const int tid = threadIdx.x;
    const int lane = tid & 63;
    const int w = tid >> 6;                  // 0..7
    const int wm = (w & 3) * 32;             // 0,32,64,96
    const int wn = (w >> 2) * 64;            // 0,64
    const int quad = lane >> 4, l16 = lane & 15;

    f32x4 acc[2][4];
    const f32x4 zero = {0.f, 0.f, 0.f, 0.f};
#pragma unroll
    for (int i = 0; i < 2; ++i)
#pragma unroll
        for (int j = 0; j < 4; ++j) acc[i][j] = zero;

    const int lrow = lane >> 2;              // 0..15
    const int lcol = (lane & 3) * 8;
    const short* gA = &A[(m0 + w*16 + lrow) * K + lcol];
    const short* gB = &B[(n0 + w*16 + lrow) * K + lcol];
    short* lA = &As[w*16][0];
    short* lB = &Bs[w*16][0];

    for (int k0 = 0; k0 < K; k0 += 32) {
        __syncthreads();
        async_lds16(gA + k0, lA);
        async_lds16(gB + k0, lB);
        __syncthreads();

        s16x8 af[2], bfr[4];
#pragma unroll
        for (int i = 0; i < 2; ++i) af[i]  = *(const s16x8*)&As[wm + i*16 + l16][quad*8];
#pragma unroll
        for (int j = 0; j < 4; ++j) bfr[j] = *(const s16x8*)&Bs[wn + j*16 + l16][quad*8];
#pragma unroll
        for (int i = 0; i < 2; ++i)
#pragma unroll
            for (int j = 0; j < 4; ++j)
                acc[i][j] = mfma16(af[i], bfr[j], acc[i][j]);
    }

#pragma unroll
    for (int j = 0; j < 4; ++j) {
        int n = n0 + wn + j*16 + l16;
        float bi = bf2f(bias[n]);
        int which = n >> 10;            // wave-uniform (wave spans 64 cols)
        int h = (n >> 6) & 15, d = n & 63;
        if (which < 2) {                // Q / K: [B,H,T,64]
            short* dst = (which == 0) ? qo : ko;
            float scl = (which == 0) ? Q_SCALE : 1.0f;
#pragma unroll
            for (int i = 0; i < 2; ++i) {
#pragma unroll
                for (int r = 0; r < 4; ++r) {
                    int m = m0 + wm + i*16 + quad*4 + r;
                    int b = m >> 11, t = m & 2047;
                    float v = (acc[i][j][r] + bi) * scl;
                    dst[(((b*16 + h) * 2048) + t) * 64 + d] = f2bf(v);
                }
            }
        } else {                        // V: write transposed [B,H,64,T]
#pragma unroll
            for (int i = 0; i < 2; ++i) {
                int m = m0 + wm + i*16 + quad*4;   // t0, %4 == 0
                int b = m >> 11, t0 = m & 2047;
                short4 o4 = { f2bf(acc[i][j][0] + bi), f2bf(acc[i][j][1] + bi),
                              f2bf(acc[i][j][2] + bi), f2bf(acc[i][j][3] + bi) };
                *(short4*)&vto[(((size_t)(b*16 + h) * 64) + d) * 2048 + t0] = o4;
            }
        }
    }
}

// ---------------------------------------------------------------------------
// Flash attention — R20 exact: paired q-tiles, gload_lds dbuf K/V, XOR
// swizzle (linear dest + pre-swizzled source + swizzled reads), MFMA-lsum.
// ---------------------------------------------------------------------------
__global__ __launch_bounds__(512) void attn_kernel(
    const short* __restrict__ Q, const short* __restrict__ K,
    const short* __restrict__ Vt, short* __restrict__ ctx)
{
    alignas(16) __shared__ short Ks2[2][64][64];   // [buf][s][d], swizzled
    alignas(16) __shared__ short Vs2[2][64][64];   // [buf][d][s], swizzled
    alignas(16) __shared__ short Pl[8][16][72];    // per-wave [q][s]

    const int bh = blockIdx.x;                    // 0..31
    const int j  = blockIdx.y;                    // 0..15
    const int tid = threadIdx.x;                  // 0..511
    const int w = tid >> 6, lane = tid & 63;
    const int quad = lane >> 4, l16 = lane & 15;
    const int b = bh >> 4, h = bh & 15;

    const int isB = w >> 2;                       // wave-uniform: 0=tile A, 1=tile B
    const int wq  = w & 3;                        // 16-row group within own tile
    const int qt  = isB ? (31 - j) : j;
    const int qbase  = qt * 64;
    const int qbaseA = j * 64;
    const int qbaseB = (31 - j) * 64;             // block-uniform loop bound

    const short* Qb  = Q  + bh * T_SEQ * 64;
    const short* Kb  = K  + bh * T_SEQ * 64;
    const short* Vbt = Vt + (size_t)bh * 64 * T_SEQ;

    const int qg = qbase + wq*16 + l16;
    const short* qrow = Qb + qg * 64;
    const s16x8 qa0 = *(const s16x8*)(qrow + quad*8);
    const s16x8 qa1 = *(const s16x8*)(qrow + 32 + quad*8);

    const s16x8 ones = { (short)0x3F80, (short)0x3F80, (short)0x3F80, (short)0x3F80,
                         (short)0x3F80, (short)0x3F80, (short)0x3F80, (short)0x3F80 };

    const f32x4 zero = {0.f, 0.f, 0.f, 0.f};
    f32x4 o[4];
#pragma unroll
    for (int dt = 0; dt < 4; ++dt) o[dt] = zero;
    f32x4 ls = zero;                              // MFMA-accumulated lsum

    // staging geometry: wave w covers rows w*8..w*8+7 (1KB per gload instr)
    const int srow   = w*8 + (lane >> 3);                    // row this lane covers
    const int schunk = ((lane & 7) ^ (lane >> 3)) * 8;       // pre-swizzled col (shorts)
    short* kdst0 = &Ks2[0][w*8][0];               // wave-uniform linear dests
    short* kdst1 = &Ks2[1][w*8][0];
    short* vdst0 = &Vs2[0][w*8][0];
    short* vdst1 = &Vs2[1][w*8][0];

    const int csw = (l16 & 7) * 8;                // fragment-read swizzle (shorts)

    // prologue: issue tile s0=0 into buf 0
    async_lds16(&Kb[srow * 64 + schunk], kdst0);
    async_lds16(&Vbt[(size_t)srow * T_SEQ + schunk], vdst0);

    int cur = 0;
    for (int s0 = 0; s0 <= qbaseB; s0 += 64) {
        __syncthreads();   // drains own gloads for tile s0; publishes; closes old reads

        if (s0 + 64 <= qbaseB) {                  // issue next tile into cur^1
            async_lds16(&Kb[(s0 + 64 + srow) * 64 + schunk], cur ? kdst0 : kdst1);
            async_lds16(&Vbt[(size_t)srow * T_SEQ + s0 + 64 + schunk], cur ? vdst0 : vdst1);
        }

        const bool act = isB || (s0 <= qbaseA);   // wave-uniform
        if (act) {
            // S^T = K Q^T
#pragma unroll
            for (int sub = 0; sub < 4; ++sub) {
                s16x8 ka0 = *(const s16x8*)&Ks2[cur][sub*16 + l16][(quad*8) ^ csw];
                s16x8 ka1 = *(const s16x8*)&Ks2[cur][sub*16 + l16][(32 + quad*8) ^ csw];
                __builtin_amdgcn_s_setprio(1);
                f32x4 S = mfma16(ka1, qa1, mfma16(ka0, qa0, zero));
                __builtin_amdgcn_s_setprio(0);
                if (s0 == qbase) {                // diagonal: causal mask
                    int sb = s0 + sub*16 + quad*4;
#pragma unroll
                    for (int r = 0; r < 4; ++r)
                        if (sb + r > qg) S[r] = NEG_BIG;
                }
                float p0 = exp2f(S[0]), p1 = exp2f(S[1]);
                float p2 = exp2f(S[2]), p3 = exp2f(S[3]);
                uint2 pk;
                pk.x = cvt_pk_bf16(p0, p1);
                pk.y = cvt_pk_bf16(p2, p3);
                *(uint2*)&Pl[w][l16][sub*16 + quad*4] = pk;
            }
            // wave-private Pl: in-order within wave, no barrier

            // O^T += V^T P^T ; lsum via ones-fragment MFMA
            s16x8 pb0 = *(const s16x8*)&Pl[w][l16][quad*8];
            s16x8 pb1 = *(const s16x8*)&Pl[w][l16][32 + quad*8];
            __builtin_amdgcn_s_setprio(1);
            ls = mfma16(ones, pb1, mfma16(ones, pb0, ls));
#pragma unroll
            for (int dt = 0; dt < 4; ++dt) {
                s16x8 va0 = *(const s16x8*)&Vs2[cur][dt*16 + l16][(quad*8) ^ csw];
                s16x8 va1 = *(const s16x8*)&Vs2[cur][dt*16 + l16][(32 + quad*8) ^ csw];
                o[dt] = mfma16(va1, pb1, mfma16(va0, pb0, o[dt]));
            }
            __builtin_amdgcn_s_setprio(0);
        }
        cur ^= 1;
    }

    float inv = 1.0f / ls[0];                     // all acc rows equal (ones A-frag)
    int base = (b * T_SEQ + qg) * D_MODEL + h * 64;
#pragma unroll
    for (int dt = 0; dt < 4; ++dt) {
        uint2 pk;
        pk.x = cvt_pk_bf16(o[dt][0] * inv, o[dt][1] * inv);
        pk.y = cvt_pk_bf16(o[dt][2] * inv, o[dt][3] * inv);
        *(uint2*)&ctx[base + dt*16 + quad*4] = pk;
    }
}

// ---------------------------------------------------------------------------
// GEMM2 (m97 2-barrier loop, BK=32, 512 threads / 8 waves): out = ctx@w_out^T
// + b_out, fp32. Wave w: rows (w&3)*32, cols (w>>2)*32. acc[2][2].
// Staging: wave w stages A rows w*16; waves 0-3 also stage B rows w*16.
// ---------------------------------------------------------------------------
__global__ __launch_bounds__(512, 4) void gemm_out_kernel(
    const short* __restrict__ A, const short* __restrict__ B,
    const short* __restrict__ bias, float* __restrict__ out)
{
    const int K = 1024;
    alignas(16) __shared__ short As[128][32];
    alignas(16) __shared__ short Bs[64][32];
    const int m0 = blockIdx.x * 128;
    const int n0 = blockIdx.y * 64;
    const int tid = threadIdx.x;
    const int lane = tid & 63;
    const int w = tid >> 6;                  // 0..7
    const int wm = (w & 3) * 32;
    const int wn = (w >> 2) * 32;
    const int quad = lane >> 4, l16 = lane & 15;

    f32x4 acc[2][2];
    const f32x4 zero = {0.f, 0.f, 0.f, 0.f};
#pragma unroll
    for (int i = 0; i < 2; ++i)
#pragma unroll
        for (int j = 0; j < 2; ++j) acc[i][j] = zero;

    const int lrow = lane >> 2;
    const int lcol = (lane & 3) * 8;
    const short* gA = &A[(m0 + w*16 + lrow) * K + lcol];
    const short* gB = &B[(n0 + (w & 3)*16 + lrow) * K + lcol];
    short* lA = &As[w*16][0];
    short* lB = &Bs[(w & 3)*16][0];
    const bool stageB = (w < 4);             // wave-uniform

    for (int k0 = 0; k0 < K; k0 += 32) {
        __syncthreads();
        async_lds16(gA + k0, lA);
        if (stageB) async_lds16(gB + k0, lB);
        __syncthreads();

        s16x8 af[2], bfr[2];
#pragma unroll
        for (int i = 0; i < 2; ++i) af[i]  = *(const s16x8*)&As[wm + i*16 + l16][quad*8];
#pragma unroll
        for (int j = 0; j < 2; ++j) bfr[j] = *(const s16x8*)&Bs[wn + j*16 + l16][quad*8];
#pragma unroll
        for (int i = 0; i < 2; ++i)
#pragma unroll
            for (int j = 0; j < 2; ++j)
                acc[i][j] = mfma16(af[i], bfr[j], acc[i][j]);
    }

#pragma unroll
    for (int j = 0; j < 2; ++j) {
        int n = n0 + wn + j*16 + l16;
        float bi = bf2f(bias[n]);
#pragma unroll
        for (int i = 0; i < 2; ++i) {
#pragma unroll
            for (int r = 0; r < 4; ++r) {
                int m = m0 + wm + i*16 + quad*4 + r;
                out[m * 1024 + n] = acc[i][j][r] + bi;
            }
        }
    }
}

// ---------------------------------------------------------------------------
extern "C" void kernel_launch(void* const* d_in, const int* in_sizes, int n_in,
                              void* d_out, int out_size, void* d_ws, size_t ws_size,
                              hipStream_t stream) {
    float* out = (float*)d_out;
    char* ws = (char*)d_ws;

    const size_t MB = 1u << 20;
    short* xb     = (short*)(ws);            // 8 MB
    short* w_inb  = (short*)(ws + 8*MB);     // 6 MB
    short* b_inb  = (short*)(ws + 14*MB);
    short* w_outb = (short*)(ws + 15*MB);    // 2 MB
    short* b_outb = (short*)(ws + 17*MB);
    short* qb     = (short*)(ws + 18*MB);    // 8 MB [B,H,T,64]
    short* kb     = (short*)(ws + 26*MB);    // 8 MB [B,H,T,64]
    short* vtb    = (short*)(ws + 34*MB);    // 8 MB [B,H,64,T] (direct from gemm)
    short* ctxb   = (short*)(ws + 42*MB);    // 8 MB [B,T,D]

    canon_all_kernel<<<(V_TOT + 255) / 256, 256, 0, stream>>>(
        (const float*)d_in[0], (const float*)d_in[1], (const float*)d_in[2],
        (const float*)d_in[3], (const float*)d_in[4],
        xb, w_inb, b_inb, w_outb, b_outb);

    gemm_qkv_kernel<<<dim3(32, 24), 512, 0, stream>>>(xb, w_inb, b_inb, qb, kb, vtb);
    attn_kernel<<<dim3(32, 16), 512, 0, stream>>>(qb, kb, vtb, ctxb);
    gemm_out_kernel<<<dim3(32, 16), 512, 0, stream>>>(ctxb, w_outb, b_outb, out);
}